// Round 5
// baseline (153.704 us; speedup 1.0000x reference)
//
#include <hip/hip_runtime.h>

#define EXTENT 7
#define CHANNELS 256
#define NPTS (EXTENT * EXTENT)  // 49

typedef float v4f __attribute__((ext_vector_type(4)));

// ---------------------------------------------------------------------------
// Kernel A: compute per-box pyramid level + spatial sort key, bitonic-sort
// 1024 boxes in one block so the main kernel can process them in (level,y,x)
// order. Any permutation is correct; sorting only affects memory locality.
// ---------------------------------------------------------------------------
__global__ __launch_bounds__(1024) void sort_boxes_kernel(
    const float* __restrict__ metadata,
    const float* __restrict__ boxes,
    int n,
    unsigned int* __restrict__ perm)
{
    __shared__ unsigned long long s[1024];
    const int t = threadIdx.x;
    const float rows = metadata[0];
    const float cols = metadata[1];

    unsigned long long key = ~0ull;
    if (t < n) {
        const float x1 = boxes[t * 4 + 0];
        const float y1 = boxes[t * 4 + 1];
        const float x2 = boxes[t * 4 + 2];
        const float y2 = boxes[t * 4 + 3];
        const float h = y2 - y1;
        const float w = x2 - x1;
        float rl = logf(sqrtf(h * w) / sqrtf(rows * cols)) / logf(2.0f);
        rl = fminf(5.0f, fmaxf(2.0f, 4.0f + rintf(rl)));
        const int lvl = (int)rl;             // 2..5
        const int H = 1 << (10 - lvl);       // 256,128,64,32
        const unsigned int yc = (unsigned int)(y1 / (rows - 1.0f) * (float)(H - 1));
        const unsigned int xc = (unsigned int)(x1 / (cols - 1.0f) * (float)(H - 1));
        key = ((unsigned long long)lvl << 40)
            | ((unsigned long long)(yc & 0xFFFu) << 28)
            | ((unsigned long long)(xc & 0xFFFu) << 16)
            | (unsigned int)t;
    }
    s[t] = key;
    __syncthreads();

    for (int k = 2; k <= 1024; k <<= 1) {
        for (int j = k >> 1; j > 0; j >>= 1) {
            const int ixj = t ^ j;
            if (ixj > t) {
                const unsigned long long a = s[t];
                const unsigned long long b = s[ixj];
                const bool up = ((t & k) == 0);
                if ((a > b) == up) { s[t] = b; s[ixj] = a; }
            }
            __syncthreads();
        }
    }
    if (t < n) perm[t] = (unsigned int)(s[t] & 0xFFFFu);
}

// ---------------------------------------------------------------------------
// Main kernel. Grid = 4 * n_boxes. rank swizzle gives XCD k the contiguous
// sorted band [k*n/8, (k+1)*n/8): its 4MB L2 serves the ~2.3x cross-box tap
// overlap, and its HBM fetches sweep the band roughly in address order.
// 256 threads: (tid&63) -> 4 channels (64 lanes x 16B = 1KB coalesced row);
// (q<<2)|(tid>>6) in [0,16) -> 3-4 of the 49 grid points.
// ---------------------------------------------------------------------------
__global__ __launch_bounds__(256) void roi_align_pyramid_kernel(
    const float* __restrict__ metadata,
    const float* __restrict__ boxes,
    const float* __restrict__ p2,
    const float* __restrict__ p3,
    const float* __restrict__ p4,
    const float* __restrict__ p5,
    float* __restrict__ out,
    const unsigned int* __restrict__ perm,
    int n_boxes)
{
    const int i   = blockIdx.x % n_boxes;
    const int q   = blockIdx.x / n_boxes;      // 0..3
    const int tid = threadIdx.x;
    const int sub = (q << 2) | (tid >> 6);     // 0..15
    const int c   = (tid & 63) << 2;           // channel offset

    // XCD banding: blockIdx%8 == i%8 (n_boxes%8==0), so band = i&7 is this
    // block's XCD under round-robin dispatch; give it a contiguous rank band.
    const int rank = (i & 7) * (n_boxes >> 3) + (i >> 3);
    const int box  = perm ? (int)perm[rank] : rank;

    const float rows = metadata[0];
    const float cols = metadata[1];

    const float x1 = boxes[box * 4 + 0];
    const float y1 = boxes[box * 4 + 1];
    const float x2 = boxes[box * 4 + 2];
    const float y2 = boxes[box * 4 + 3];

    // Level selection — replicate reference fp32 math.
    const float h = y2 - y1;
    const float w = x2 - x1;
    float roi_level = logf(sqrtf(h * w) / sqrtf(rows * cols)) / logf(2.0f);
    roi_level = fminf(5.0f, fmaxf(2.0f, 4.0f + rintf(roi_level)));
    const int lvl = (int)roi_level;  // 2..5

    const float* feat;
    int H;
    if      (lvl == 2) { feat = p2; H = 256; }
    else if (lvl == 3) { feat = p3; H = 128; }
    else if (lvl == 4) { feat = p4; H = 64; }
    else               { feat = p5; H = 32; }
    const int W = H;

    const float ny1 = y1 / (rows - 1.0f);
    const float ny2 = y2 / (rows - 1.0f);
    const float nx1 = x1 / (cols - 1.0f);
    const float nx2 = x2 / (cols - 1.0f);

    float* outp = out + (size_t)box * NPTS * CHANNELS + c;

    auto process = [&](int p) {
        const int gy = p / EXTENT;
        const int gx = p - gy * EXTENT;

        const float gyf = (float)gy / (float)(EXTENT - 1);
        const float ysv = (ny1 + (ny2 - ny1) * gyf) * (float)(H - 1);
        float y0f = floorf(ysv);
        y0f = fminf(fmaxf(y0f, 0.0f), (float)(H - 2));
        const int   y0 = (int)y0f;
        const float wy = ysv - y0f;

        const float gxf = (float)gx / (float)(EXTENT - 1);
        const float xsv = (nx1 + (nx2 - nx1) * gxf) * (float)(W - 1);
        float x0f = floorf(xsv);
        x0f = fminf(fmaxf(x0f, 0.0f), (float)(W - 2));
        const int   x0 = (int)x0f;
        const float wx = xsv - x0f;

        const float* base = feat + ((size_t)(y0 * W + x0)) * CHANNELS + c;
        const v4f f00 = *(const v4f*)(base);
        const v4f f01 = *(const v4f*)(base + CHANNELS);
        const v4f f10 = *(const v4f*)(base + (size_t)W * CHANNELS);
        const v4f f11 = *(const v4f*)(base + (size_t)W * CHANNELS + CHANNELS);

        const float w00 = (1.0f - wy) * (1.0f - wx);
        const float w01 = (1.0f - wy) * wx;
        const float w10 = wy * (1.0f - wx);
        const float w11 = wy * wx;

        v4f r = f00 * w00 + f01 * w01 + f10 * w10 + f11 * w11;

        // Write-once: keep feature lines resident in L2.
        __builtin_nontemporal_store(r, (v4f*)(outp + (size_t)p * CHANNELS));
    };

    #pragma unroll
    for (int k = 0; k < 3; ++k) {
        process(sub + 16 * k);
    }
    if (sub == 0) {
        process(48);
    }
}

extern "C" void kernel_launch(void* const* d_in, const int* in_sizes, int n_in,
                              void* d_out, int out_size, void* d_ws, size_t ws_size,
                              hipStream_t stream) {
    const float* metadata = (const float*)d_in[0];
    const float* boxes    = (const float*)d_in[1];
    const float* p2       = (const float*)d_in[2];
    const float* p3       = (const float*)d_in[3];
    const float* p4       = (const float*)d_in[4];
    const float* p5       = (const float*)d_in[5];
    float* out = (float*)d_out;

    const int n_boxes = in_sizes[1] / 4;  // 1024

    unsigned int* perm = nullptr;
    if (ws_size >= (size_t)n_boxes * sizeof(unsigned int) && n_boxes <= 1024) {
        perm = (unsigned int*)d_ws;
        sort_boxes_kernel<<<1, 1024, 0, stream>>>(metadata, boxes, n_boxes, perm);
    }

    dim3 grid(n_boxes * 4);
    dim3 block(256);
    roi_align_pyramid_kernel<<<grid, block, 0, stream>>>(
        metadata, boxes, p2, p3, p4, p5, out, perm, n_boxes);
}

// Round 6
// 144.332 us; speedup vs baseline: 1.0649x; 1.0649x over previous
//
#include <hip/hip_runtime.h>

#define EXTENT 7
#define CHANNELS 256
#define NPTS (EXTENT * EXTENT)   // 49
#define NV4  (NPTS * 64)         // 3136 v4f = 50176 B output tile per box

typedef float v4f __attribute__((ext_vector_type(4)));

// One block per box. Phase 1: 4 waves x (12|13) grid points, scattered tap
// reads only, results staged in LDS (49KB tile). Phase 2 (after one barrier):
// pure streaming write of the contiguous 49KB tile. Rationale: R0-R4 showed
// time invariant to occupancy/ILP/order at ~41us (2.2 TB/s read + 1.2 TB/s
// write); the untested variable is fine-grained R/W interleave at the memory
// controller — this kernel separates the streams.
__global__ __launch_bounds__(256) void roi_align_pyramid_kernel(
    const float* __restrict__ metadata,
    const float* __restrict__ boxes,
    const float* __restrict__ p2,
    const float* __restrict__ p3,
    const float* __restrict__ p4,
    const float* __restrict__ p5,
    float* __restrict__ out)
{
    __shared__ v4f smem[NV4];   // 50176 bytes: the box's 7x7x256 output tile

    const int box = blockIdx.x;
    const int tid = threadIdx.x;
    const int sub = tid >> 6;        // wave id 0..3
    const int c   = (tid & 63) << 2; // channel offset

    const float rows = metadata[0];
    const float cols = metadata[1];

    const float x1 = boxes[box * 4 + 0];
    const float y1 = boxes[box * 4 + 1];
    const float x2 = boxes[box * 4 + 2];
    const float y2 = boxes[box * 4 + 3];

    // Level selection — replicate reference fp32 math.
    const float h = y2 - y1;
    const float w = x2 - x1;
    float roi_level = logf(sqrtf(h * w) / sqrtf(rows * cols)) / logf(2.0f);
    roi_level = fminf(5.0f, fmaxf(2.0f, 4.0f + rintf(roi_level)));
    const int lvl = (int)roi_level;  // 2..5

    const float* feat;
    int H;
    if      (lvl == 2) { feat = p2; H = 256; }
    else if (lvl == 3) { feat = p3; H = 128; }
    else if (lvl == 4) { feat = p4; H = 64; }
    else               { feat = p5; H = 32; }
    const int W = H;

    const float ny1 = y1 / (rows - 1.0f);
    const float ny2 = y2 / (rows - 1.0f);
    const float nx1 = x1 / (cols - 1.0f);
    const float nx2 = x2 / (cols - 1.0f);

    auto process = [&](int p) {
        const int gy = p / EXTENT;
        const int gx = p - gy * EXTENT;

        const float gyf = (float)gy / (float)(EXTENT - 1);
        const float ysv = (ny1 + (ny2 - ny1) * gyf) * (float)(H - 1);
        float y0f = floorf(ysv);
        y0f = fminf(fmaxf(y0f, 0.0f), (float)(H - 2));
        const int   y0 = (int)y0f;
        const float wy = ysv - y0f;

        const float gxf = (float)gx / (float)(EXTENT - 1);
        const float xsv = (nx1 + (nx2 - nx1) * gxf) * (float)(W - 1);
        float x0f = floorf(xsv);
        x0f = fminf(fmaxf(x0f, 0.0f), (float)(W - 2));
        const int   x0 = (int)x0f;
        const float wx = xsv - x0f;

        const float* base = feat + ((size_t)(y0 * W + x0)) * CHANNELS + c;
        const v4f f00 = *(const v4f*)(base);
        const v4f f01 = *(const v4f*)(base + CHANNELS);
        const v4f f10 = *(const v4f*)(base + (size_t)W * CHANNELS);
        const v4f f11 = *(const v4f*)(base + (size_t)W * CHANNELS + CHANNELS);

        const float w00 = (1.0f - wy) * (1.0f - wx);
        const float w01 = (1.0f - wy) * wx;
        const float w10 = wy * (1.0f - wx);
        const float w11 = wy * wx;

        // Stage in LDS: lane-contiguous 16B -> 2 lanes/bank (free, m136).
        smem[p * 64 + (tid & 63)] = f00 * w00 + f01 * w01 + f10 * w10 + f11 * w11;
    };

    // Phase 1: reads only. 49 points: sub + 4k, k<12; p=48 by wave 0.
    #pragma unroll 4
    for (int k = 0; k < 12; ++k) {
        process(sub + 4 * k);
    }
    if (sub == 0) {
        process(48);
    }

    __syncthreads();

    // Phase 2: pure streaming write of the 49KB tile (contiguous per box).
    v4f* outp = (v4f*)out + (size_t)box * NV4;
    #pragma unroll 7
    for (int k = 0; k < NV4 / 256; ++k) {   // 3136/256 = 12.25 -> 12 full + tail
        const int idx = k * 256 + tid;
        __builtin_nontemporal_store(smem[idx], outp + idx);
    }
    {
        const int idx = 12 * 256 + tid;     // tail: 3072..3135
        if (idx < NV4)
            __builtin_nontemporal_store(smem[idx], outp + idx);
    }
}

extern "C" void kernel_launch(void* const* d_in, const int* in_sizes, int n_in,
                              void* d_out, int out_size, void* d_ws, size_t ws_size,
                              hipStream_t stream) {
    const float* metadata = (const float*)d_in[0];
    const float* boxes    = (const float*)d_in[1];
    const float* p2       = (const float*)d_in[2];
    const float* p3       = (const float*)d_in[3];
    const float* p4       = (const float*)d_in[4];
    const float* p5       = (const float*)d_in[5];
    float* out = (float*)d_out;

    const int n_boxes = in_sizes[1] / 4;  // 1024
    dim3 grid(n_boxes);
    dim3 block(256);
    roi_align_pyramid_kernel<<<grid, block, 0, stream>>>(
        metadata, boxes, p2, p3, p4, p5, out);
}